// Round 6
// baseline (409.104 us; speedup 1.0000x reference)
//
#include <hip/hip_runtime.h>
#include <cstddef>

#define H 256
#define NHEADS 8
#define HD 32

typedef __attribute__((ext_vector_type(8))) short bf16x8;
typedef __attribute__((ext_vector_type(4))) float f32x4;

__device__ __forceinline__ float bfe2f(short s) {
    unsigned u = ((unsigned)(unsigned short)s) << 16; return __builtin_bit_cast(float, u);
}
__device__ __forceinline__ unsigned short f2bf(float x) {
    unsigned u = __builtin_bit_cast(unsigned, x);
    u += 0x7fffu + ((u >> 16) & 1u);           // round-to-nearest-even
    return (unsigned short)(u >> 16);
}

// ---------------------------------------------------------------------------
// K1: exclusive prefix sums of lens + zero stats (4 x 256 floats)
// ---------------------------------------------------------------------------
__global__ __launch_bounds__(512) void scan_zero_kernel(
    const int* __restrict__ slen, const int* __restrict__ dlen,
    int* __restrict__ soff, int* __restrict__ doff,
    float* __restrict__ stats, int B)
{
    __shared__ int ss[512], dd[512];
    const int t = threadIdx.x;
    const int sv = (t < B) ? slen[t] : 0;
    const int dv = (t < B) ? dlen[t] : 0;
    ss[t] = sv; dd[t] = dv;
    __syncthreads();
    for (int o = 1; o < 512; o <<= 1) {
        int a = (t >= o) ? ss[t - o] : 0;
        int b = (t >= o) ? dd[t - o] : 0;
        __syncthreads();
        ss[t] += a; dd[t] += b;
        __syncthreads();
    }
    if (t < B) { soff[t] = ss[t] - sv; doff[t] = dd[t] - dv; }
    stats[t] = 0.f;
    stats[t + 512] = 0.f;
}

// ---------------------------------------------------------------------------
// prepass: [N,256] f32 (f = d*8+h) -> per-head bf16 planes T[h][n][32];
// blockIdx.y==0: src -> KT + d-major VT2[h][32][n]; ==1: dst -> QT.
// ---------------------------------------------------------------------------
__global__ __launch_bounds__(256) void prepass_kernel(
    const float* __restrict__ src, const float* __restrict__ dst,
    unsigned short* __restrict__ KT, unsigned short* __restrict__ VT2,
    unsigned short* __restrict__ QT, int N)
{
    __shared__ unsigned short pl[8 * 64 * 40];   // [h][row][d], stride 40
    const int t = threadIdx.x;
    const int rb = blockIdx.x * 64;
    const int isrc = (blockIdx.y == 0);
    const float* __restrict__ in = isrc ? src : dst;
    unsigned short* __restrict__ T = isrc ? KT : QT;
    #pragma unroll
    for (int i = 0; i < 16; ++i) {
        const int idx = t + i * 256;             // 4096 float4s
        const int row = idx >> 6, f4 = idx & 63;
        const float4 v = ((const float4*)in)[(size_t)(rb + row) * 64 + f4];
        const int f0 = f4 * 4, h0 = f0 & 7, d = f0 >> 3;
        pl[(h0 + 0) * 2560 + row * 40 + d] = f2bf(v.x);
        pl[(h0 + 1) * 2560 + row * 40 + d] = f2bf(v.y);
        pl[(h0 + 2) * 2560 + row * 40 + d] = f2bf(v.z);
        pl[(h0 + 3) * 2560 + row * 40 + d] = f2bf(v.w);
    }
    __syncthreads();
    #pragma unroll
    for (int i = 0; i < 8; ++i) {
        const int idx = t + i * 256;             // 2048 16B chunks
        const int h = idx >> 8, rem = idx & 255, row = rem >> 2, c = rem & 3;
        const bf16x8 val = *(const bf16x8*)&pl[h * 2560 + row * 40 + c * 8];
        *(bf16x8*)&T[(size_t)(h * N + rb + row) * 32 + c * 8] = val;
    }
    if (isrc) {
        #pragma unroll
        for (int i = 0; i < 8; ++i) {
            const int idx = t + i * 256;         // 8 planes x 32 d x 8 n-chunks
            const int h = idx >> 8, rem = idx & 255, d = rem >> 3, nc = rem & 7;
            unsigned short tmp[8];
            #pragma unroll
            for (int j = 0; j < 8; ++j) tmp[j] = pl[h * 2560 + (nc * 8 + j) * 40 + d];
            ushort4 lo, hi;
            lo.x = tmp[0]; lo.y = tmp[1]; lo.z = tmp[2]; lo.w = tmp[3];
            hi.x = tmp[4]; hi.y = tmp[5]; hi.z = tmp[6]; hi.w = tmp[7];
            *(ushort4*)&VT2[(size_t)(h * 32 + d) * N + rb + nc * 8] = lo;
            *(ushort4*)&VT2[(size_t)(h * 32 + d) * N + rb + nc * 8 + 4] = hi;
        }
    }
}

// ---------------------------------------------------------------------------
// weights cvt: W1 with K-permutation (kp = half*256 + h*32 + d), W2 plain.
// ---------------------------------------------------------------------------
__global__ __launch_bounds__(256) void cvtW_kernel(
    const float* __restrict__ W1, const float* __restrict__ W2,
    unsigned short* __restrict__ W1p, unsigned short* __restrict__ W2bf)
{
    const int idx = blockIdx.x * 256 + threadIdx.x;
    if (idx < 131072) {
        const int kp = idx & 511, c = idx >> 9;
        const int half = kp >> 8, r = kp & 255, hh = r >> 5, d = r & 31;
        W1p[(size_t)c * 512 + kp] = f2bf(W1[(size_t)c * 512 + half * 256 + d * 8 + hh]);
    } else {
        const int i2 = idx - 131072;
        W2bf[i2] = f2bf(W2[i2]);
    }
}

// ---------------------------------------------------------------------------
// K2: MFMA attention (one wave per (graph, head)); unchanged from R4.
// ---------------------------------------------------------------------------
template<int LS>
__device__ __forceinline__ void attn_body(
    const unsigned short* __restrict__ KT, const unsigned short* __restrict__ QT,
    const unsigned short* __restrict__ VT2, unsigned short* __restrict__ OT,
    unsigned short* __restrict__ Ps, int N, int so, int df, int Ld, int h, int lane)
{
    constexpr int MT = LS / 16, CH = LS / 32;
    const int lr = lane & 15, lq = lane >> 4;
    const float iscale = 0.17677669529663687f;  // 1/sqrt(32)

    bf16x8 kf[MT];
    #pragma unroll
    for (int mt = 0; mt < MT; ++mt)
        kf[mt] = *(const bf16x8*)&KT[(size_t)(h * N + so + mt * 16 + lr) * 32 + lq * 8];
    bf16x8 vf[CH][2];
    #pragma unroll
    for (int c = 0; c < CH; ++c)
        #pragma unroll
        for (int dt = 0; dt < 2; ++dt)
            vf[c][dt] = *(const bf16x8*)&VT2[(size_t)(h * 32 + dt * 16 + lr) * N + so + c * 32 + lq * 8];

    const int NT = Ld >> 4;
    for (int nt = 0; nt < NT; ++nt) {
        const bf16x8 qf = *(const bf16x8*)&QT[(size_t)(h * N + df + nt * 16 + lr) * 32 + lq * 8];
        f32x4 s[MT];
        #pragma unroll
        for (int mt = 0; mt < MT; ++mt) {
            f32x4 z = {0.f, 0.f, 0.f, 0.f};
            s[mt] = __builtin_amdgcn_mfma_f32_16x16x32_bf16(kf[mt], qf, z, 0, 0, 0);
        }
        float mx = -INFINITY;
        #pragma unroll
        for (int mt = 0; mt < MT; ++mt)
            mx = fmaxf(mx, fmaxf(fmaxf(s[mt][0], s[mt][1]), fmaxf(s[mt][2], s[mt][3])));
        mx = fmaxf(mx, __shfl_xor(mx, 16));
        mx = fmaxf(mx, __shfl_xor(mx, 32));
        const float mxi = mx * iscale;
        float sum = 0.f;
        #pragma unroll
        for (int mt = 0; mt < MT; ++mt) {
            #pragma unroll
            for (int r = 0; r < 4; ++r) {
                const float e = __expf(s[mt][r] * iscale - mxi);
                s[mt][r] = e; sum += e;
            }
        }
        sum += __shfl_xor(sum, 16);
        sum += __shfl_xor(sum, 32);
        const float rinv = 1.f / sum;
        #pragma unroll
        for (int mt = 0; mt < MT; ++mt) {
            uint2 p;
            p.x = ((unsigned)f2bf(s[mt][0])) | (((unsigned)f2bf(s[mt][1])) << 16);
            p.y = ((unsigned)f2bf(s[mt][2])) | (((unsigned)f2bf(s[mt][3])) << 16);
            *(uint2*)&Ps[lr * 136 + mt * 16 + lq * 4] = p;
        }
        __asm__ volatile("" ::: "memory");
        __builtin_amdgcn_wave_barrier();
        f32x4 o0 = {0.f, 0.f, 0.f, 0.f}, o1 = {0.f, 0.f, 0.f, 0.f};
        #pragma unroll
        for (int c = 0; c < CH; ++c) {
            const bf16x8 pa = *(const bf16x8*)&Ps[lr * 136 + c * 32 + lq * 8];
            o0 = __builtin_amdgcn_mfma_f32_16x16x32_bf16(pa, vf[c][0], o0, 0, 0, 0);
            o1 = __builtin_amdgcn_mfma_f32_16x16x32_bf16(pa, vf[c][1], o1, 0, 0, 0);
        }
        __asm__ volatile("" ::: "memory");
        __builtin_amdgcn_wave_barrier();
        #pragma unroll
        for (int r = 0; r < 4; ++r) {
            const float rv = __shfl(rinv, lq * 4 + r);
            const int row = df + nt * 16 + lq * 4 + r;
            OT[(size_t)(h * N + row) * 32 + lr]      = f2bf(o0[r] * rv);
            OT[(size_t)(h * N + row) * 32 + 16 + lr] = f2bf(o1[r] * rv);
        }
    }
}

__global__ __launch_bounds__(256) void attn_mfma(
    const unsigned short* __restrict__ KT, const unsigned short* __restrict__ QT,
    const unsigned short* __restrict__ VT2, unsigned short* __restrict__ OT,
    const int* __restrict__ soff, const int* __restrict__ doff,
    const int* __restrict__ slen, const int* __restrict__ dlen, int N)
{
    __shared__ unsigned short Ps[4][16 * 136];
    const int b = blockIdx.x >> 1, half = blockIdx.x & 1;
    const int w = threadIdx.x >> 6, lane = threadIdx.x & 63;
    const int h = half * 4 + w;
    const int Ls = slen[b], Ld = dlen[b], so = soff[b], df = doff[b];
    switch (Ls) {
        case 32:  attn_body<32> (KT, QT, VT2, OT, Ps[w], N, so, df, Ld, h, lane); break;
        case 64:  attn_body<64> (KT, QT, VT2, OT, Ps[w], N, so, df, Ld, h, lane); break;
        case 96:  attn_body<96> (KT, QT, VT2, OT, Ps[w], N, so, df, Ld, h, lane); break;
        default:  attn_body<128>(KT, QT, VT2, OT, Ps[w], N, so, df, Ld, h, lane); break;
    }
}

// ---------------------------------------------------------------------------
// K3: GEMM1 direct-fragment, barrier-free. A = W1p rows (out cols),
// B = activation rows (QT|OT per-head planes). D[col-quad][act row].
// Each wave: 64 act rows x 64 out cols. Fused col stats + bf16 store.
// ---------------------------------------------------------------------------
__global__ __launch_bounds__(256) void gemm1_direct(
    const unsigned short* __restrict__ QT, const unsigned short* __restrict__ OT,
    const unsigned short* __restrict__ W, const float* __restrict__ bias,
    unsigned short* __restrict__ out, float* __restrict__ sum, float* __restrict__ sq,
    int N)
{
    const int tid = threadIdx.x;
    const int w = tid >> 6, lane = tid & 63;
    const int lr = lane & 15, lq = lane >> 4;
    const int wm = w >> 1, wn = w & 1;
    const int actBase = blockIdx.y * 128 + wm * 64;
    const int colBase = blockIdx.x * 128 + wn * 64;

    f32x4 acc[4][4];   // [i = col tile][j = act tile]
    #pragma unroll
    for (int i = 0; i < 4; ++i)
        #pragma unroll
        for (int j = 0; j < 4; ++j) { f32x4 z = {0.f, 0.f, 0.f, 0.f}; acc[i][j] = z; }

    for (int kk = 0; kk < 16; ++kk) {
        const unsigned short* __restrict__ actp = (kk < 8) ? QT : OT;
        const int hh = kk & 7;
        bf16x8 aw[4], ba[4];
        #pragma unroll
        for (int i = 0; i < 4; ++i)
            aw[i] = *(const bf16x8*)&W[(size_t)(colBase + i * 16 + lr) * 512 + kk * 32 + lq * 8];
        #pragma unroll
        for (int j = 0; j < 4; ++j)
            ba[j] = *(const bf16x8*)&actp[(size_t)(hh * N + actBase + j * 16 + lr) * 32 + lq * 8];
        #pragma unroll
        for (int i = 0; i < 4; ++i)
            #pragma unroll
            for (int j = 0; j < 4; ++j)
                acc[i][j] = __builtin_amdgcn_mfma_f32_16x16x32_bf16(aw[i], ba[j], acc[i][j], 0, 0, 0);
    }

    #pragma unroll
    for (int i = 0; i < 4; ++i) {
        const int c0 = colBase + i * 16 + lq * 4;
        const float4 b4 = *(const float4*)&bias[c0];
        float cs[4] = {0.f, 0.f, 0.f, 0.f}, cq[4] = {0.f, 0.f, 0.f, 0.f};
        #pragma unroll
        for (int j = 0; j < 4; ++j) {
            const int row = actBase + j * 16 + lr;
            float v[4];
            v[0] = acc[i][j][0] + b4.x; v[1] = acc[i][j][1] + b4.y;
            v[2] = acc[i][j][2] + b4.z; v[3] = acc[i][j][3] + b4.w;
            ushort4 o;
            o.x = f2bf(v[0]); o.y = f2bf(v[1]); o.z = f2bf(v[2]); o.w = f2bf(v[3]);
            *(ushort4*)&out[(size_t)row * 256 + c0] = o;
            #pragma unroll
            for (int r = 0; r < 4; ++r) { cs[r] += v[r]; cq[r] += v[r] * v[r]; }
        }
        #pragma unroll
        for (int r = 0; r < 4; ++r) {
            float s = cs[r], q = cq[r];
            s += __shfl_xor(s, 1); s += __shfl_xor(s, 2); s += __shfl_xor(s, 4); s += __shfl_xor(s, 8);
            q += __shfl_xor(q, 1); q += __shfl_xor(q, 2); q += __shfl_xor(q, 4); q += __shfl_xor(q, 8);
            if (lr == 0) { atomicAdd(&sum[c0 + r], s); atomicAdd(&sq[c0 + r], q); }
        }
    }
}

// ---------------------------------------------------------------------------
// K5: GEMM2 direct-fragment, barrier-free K-loop; BN1+ReLU fused on the
// B-operand load (scale/shift table built once per block in LDS).
// ---------------------------------------------------------------------------
__global__ __launch_bounds__(256) void gemm2_direct(
    const unsigned short* __restrict__ Y1,
    const unsigned short* __restrict__ W, const float* __restrict__ bias,
    const float* __restrict__ sum1, const float* __restrict__ sq1,
    const float* __restrict__ gamma1, const float* __restrict__ beta1,
    unsigned short* __restrict__ out, float* __restrict__ sum, float* __restrict__ sq,
    float invN)
{
    __shared__ float sc1s[256], sh1s[256];
    const int tid = threadIdx.x;
    {
        const float mean = sum1[tid] * invN;
        const float var  = sq1[tid] * invN - mean * mean;
        const float rstd = rsqrtf(var + 1e-5f);
        const float s = gamma1[tid] * rstd;
        sc1s[tid] = s;
        sh1s[tid] = beta1[tid] - mean * s;
    }
    __syncthreads();   // only barrier

    const int w = tid >> 6, lane = tid & 63;
    const int lr = lane & 15, lq = lane >> 4;
    const int wm = w >> 1, wn = w & 1;
    const int actBase = blockIdx.y * 128 + wm * 64;
    const int colBase = blockIdx.x * 128 + wn * 64;

    f32x4 acc[4][4];
    #pragma unroll
    for (int i = 0; i < 4; ++i)
        #pragma unroll
        for (int j = 0; j < 4; ++j) { f32x4 z = {0.f, 0.f, 0.f, 0.f}; acc[i][j] = z; }

    for (int kk = 0; kk < 8; ++kk) {
        const int kc0 = kk * 32 + lq * 8;
        const float4 sA = *(const float4*)&sc1s[kc0];
        const float4 sB = *(const float4*)&sc1s[kc0 + 4];
        const float4 hA = *(const float4*)&sh1s[kc0];
        const float4 hB = *(const float4*)&sh1s[kc0 + 4];
        const float sc[8] = {sA.x, sA.y, sA.z, sA.w, sB.x, sB.y, sB.z, sB.w};
        const float sh[8] = {hA.x, hA.y, hA.z, hA.w, hB.x, hB.y, hB.z, hB.w};
        bf16x8 aw[4], ba[4];
        #pragma unroll
        for (int i = 0; i < 4; ++i)
            aw[i] = *(const bf16x8*)&W[(size_t)(colBase + i * 16 + lr) * 256 + kc0];
        #pragma unroll
        for (int j = 0; j < 4; ++j) {
            const bf16x8 raw = *(const bf16x8*)&Y1[(size_t)(actBase + j * 16 + lr) * 256 + kc0];
            bf16x8 bb;
            #pragma unroll
            for (int t = 0; t < 8; ++t)
                bb[t] = (short)f2bf(fmaxf(bfe2f(raw[t]) * sc[t] + sh[t], 0.f));
            ba[j] = bb;
        }
        #pragma unroll
        for (int i = 0; i < 4; ++i)
            #pragma unroll
            for (int j = 0; j < 4; ++j)
                acc[i][j] = __builtin_amdgcn_mfma_f32_16x16x32_bf16(aw[i], ba[j], acc[i][j], 0, 0, 0);
    }

    #pragma unroll
    for (int i = 0; i < 4; ++i) {
        const int c0 = colBase + i * 16 + lq * 4;
        const float4 b4 = *(const float4*)&bias[c0];
        float cs[4] = {0.f, 0.f, 0.f, 0.f}, cq[4] = {0.f, 0.f, 0.f, 0.f};
        #pragma unroll
        for (int j = 0; j < 4; ++j) {
            const int row = actBase + j * 16 + lr;
            float v[4];
            v[0] = acc[i][j][0] + b4.x; v[1] = acc[i][j][1] + b4.y;
            v[2] = acc[i][j][2] + b4.z; v[3] = acc[i][j][3] + b4.w;
            ushort4 o;
            o.x = f2bf(v[0]); o.y = f2bf(v[1]); o.z = f2bf(v[2]); o.w = f2bf(v[3]);
            *(ushort4*)&out[(size_t)row * 256 + c0] = o;
            #pragma unroll
            for (int r = 0; r < 4; ++r) { cs[r] += v[r]; cq[r] += v[r] * v[r]; }
        }
        #pragma unroll
        for (int r = 0; r < 4; ++r) {
            float s = cs[r], q = cq[r];
            s += __shfl_xor(s, 1); s += __shfl_xor(s, 2); s += __shfl_xor(s, 4); s += __shfl_xor(s, 8);
            q += __shfl_xor(q, 1); q += __shfl_xor(q, 2); q += __shfl_xor(q, 4); q += __shfl_xor(q, 8);
            if (lr == 0) { atomicAdd(&sum[c0 + r], s); atomicAdd(&sq[c0 + r], q); }
        }
    }
}

// ---------------------------------------------------------------------------
// epilogue: out = dst + bn2(y2bf), finalize inlined. 8 elems/thread.
// ---------------------------------------------------------------------------
__global__ __launch_bounds__(256) void epilogue_kernel(
    const float* __restrict__ dst, const unsigned short* __restrict__ y2,
    const float* __restrict__ sum, const float* __restrict__ sq,
    const float* __restrict__ gamma, const float* __restrict__ beta,
    float* __restrict__ out, int n8, float invN)
{
    const int i = blockIdx.x * 256 + threadIdx.x;
    if (i >= n8) return;
    const int j0 = (i & 31) * 8;
    const bf16x8 yv = ((const bf16x8*)y2)[i];
    const float4 d0 = ((const float4*)dst)[2 * i];
    const float4 d1 = ((const float4*)dst)[2 * i + 1];
    float o[8];
    const float dv[8] = {d0.x, d0.y, d0.z, d0.w, d1.x, d1.y, d1.z, d1.w};
    #pragma unroll
    for (int j = 0; j < 8; ++j) {
        const float mean = sum[j0 + j] * invN;
        const float var  = sq[j0 + j] * invN - mean * mean;
        const float rstd = rsqrtf(var + 1e-5f);
        const float sc = gamma[j0 + j] * rstd;
        const float sh = beta[j0 + j] - mean * sc;
        o[j] = dv[j] + bfe2f(yv[j]) * sc + sh;
    }
    float4 o0, o1;
    o0.x = o[0]; o0.y = o[1]; o0.z = o[2]; o0.w = o[3];
    o1.x = o[4]; o1.y = o[5]; o1.z = o[6]; o1.w = o[7];
    ((float4*)out)[2 * i]     = o0;
    ((float4*)out)[2 * i + 1] = o1;
}

// ---------------------------------------------------------------------------
extern "C" void kernel_launch(void* const* d_in, const int* in_sizes, int n_in,
                              void* d_out, int out_size, void* d_ws, size_t ws_size,
                              hipStream_t stream)
{
    const float* src_h  = (const float*)d_in[0];
    const float* dst_h  = (const float*)d_in[1];
    const int*   slen   = (const int*)d_in[2];
    const int*   dlen   = (const int*)d_in[3];
    const float* W1     = (const float*)d_in[4];
    const float* b1     = (const float*)d_in[5];
    const float* gamma1 = (const float*)d_in[6];
    const float* beta1  = (const float*)d_in[7];
    const float* W2     = (const float*)d_in[8];
    const float* b2     = (const float*)d_in[9];
    const float* gamma2 = (const float*)d_in[10];
    const float* beta2  = (const float*)d_in[11];
    float* out = (float*)d_out;

    const int N = in_sizes[1] / H;     // 40960
    const int B = in_sizes[2];         // 512

    // ---- workspace layout (bytes) ----
    char* base = (char*)d_ws;
    int*   soff   = (int*)(base + 0);            // 2KB
    int*   doff   = (int*)(base + 2048);         // 2KB
    float* stats  = (float*)(base + 4096);       // 4KB: sum1, sq1, sum2, sq2
    unsigned short* W1p  = (unsigned short*)(base + 16384);            // 256KB
    unsigned short* W2bf = (unsigned short*)(base + 16384 + 262144);   // 128KB
    const size_t S = (size_t)N * H * sizeof(unsigned short);           // 21 MB
    char* big = base + (1 << 20);
    unsigned short* KT  = (unsigned short*)(big);
    unsigned short* VT2 = (unsigned short*)(big + S);
    unsigned short* QT  = (unsigned short*)(big + 2 * S);
    unsigned short* OT  = (unsigned short*)(big + 3 * S);
    unsigned short* y1bf = KT;    // reuse after attention (gemm1 reads QT/OT)
    unsigned short* y2bf = QT;    // reuse after gemm1 (gemm2 reads y1bf)

    const float invN = 1.0f / (float)N;

    scan_zero_kernel<<<1, 512, 0, stream>>>(slen, dlen, soff, doff, stats, B);

    prepass_kernel<<<dim3(N / 64, 2), 256, 0, stream>>>(src_h, dst_h, KT, VT2, QT, N);
    cvtW_kernel<<<768, 256, 0, stream>>>(W1, W2, W1p, W2bf);

    attn_mfma<<<B * 2, 256, 0, stream>>>(KT, QT, VT2, OT, soff, doff, slen, dlen, N);

    dim3 ggrid(H / 128, N / 128);     // (2, 320)
    gemm1_direct<<<ggrid, 256, 0, stream>>>(QT, OT, W1p, b1, y1bf, stats + 0, stats + 256, N);

    gemm2_direct<<<ggrid, 256, 0, stream>>>(y1bf, W2bf, b2, stats + 0, stats + 256,
                                            gamma1, beta1, y2bf, stats + 512, stats + 768, invN);

    const int n8 = N * H / 8;
    epilogue_kernel<<<(n8 + 255) / 256, 256, 0, stream>>>(
        dst_h, y2bf, stats + 512, stats + 768, gamma2, beta2, out, n8, invN);
}